// Round 1
// baseline (454.064 us; speedup 1.0000x reference)
//
#include <hip/hip_runtime.h>

namespace {

constexpr int HH  = 48;    // H = W = T
constexpr int DIM = 384;
constexpr int NH  = 6;
constexpr int HD  = 64;
constexpr int K3  = 27;
constexpr float SCALE = 0.125f;   // HD^-0.5

constexpr int TX = 4, TY = 4, TZ = 4;
constexpr int CX = TX + 2, CY = TY + 2, CZ = TZ + 2;   // 6,6,6 halo
constexpr int NCOL = CX * CY * CZ;                      // 216 columns
constexpr int CSTRIDE = 17;                             // float4 units; pad breaks bank conflicts
constexpr int TILES = (HH/TX) * (HH/TY) * (HH/TZ);      // 1728

__device__ __forceinline__ float dot4(float4 a, float4 b) {
    return fmaf(a.x, b.x, fmaf(a.y, b.y, fmaf(a.z, b.z, a.w * b.w)));
}

__global__ __launch_bounds__(256, 2)
void natten3d(const float* __restrict__ q, const float* __restrict__ k,
              const float* __restrict__ rpb, const float* __restrict__ vv,
              float* __restrict__ out)
{
    __shared__ float4 lk[NCOL * CSTRIDE];   // 58,752 B

    const int bid  = blockIdx.x;
    const int tile = bid % TILES;
    const int n    = (bid / TILES) % NH;
    const int b    = bid / (TILES * NH);
    const int tz = (tile % (HH/TZ)) * TZ;
    const int ty = ((tile / (HH/TZ)) % (HH/TY)) * TY;
    const int tx = (tile / ((HH/TZ) * (HH/TY))) * TX;

    // ---- stage k halo (head n slice) into LDS; OOB columns = 0 (matches zero-pad) ----
    const float* kb = k + (size_t)b * HH*HH*HH * DIM + n * HD;
    for (int idx = threadIdx.x; idx < NCOL * 16; idx += 256) {
        const int col = idx >> 4, c16 = idx & 15;
        const int cz = col % CZ, cy = (col / CZ) % CY, cx = col / (CZ * CY);
        const int gx = tx + cx - 1, gy = ty + cy - 1, gz = tz + cz - 1;
        float4 val = make_float4(0.f, 0.f, 0.f, 0.f);
        if ((unsigned)gx < (unsigned)HH && (unsigned)gy < (unsigned)HH &&
            (unsigned)gz < (unsigned)HH) {
            val = *reinterpret_cast<const float4*>(
                kb + (size_t)((gx * HH + gy) * HH + gz) * DIM + c16 * 4);
        }
        lk[col * CSTRIDE + c16] = val;
    }
    __syncthreads();

    // ---- compute: 64 positions x 4-lane d-split ----
    const int pos = threadIdx.x >> 2;
    const int qr  = threadIdx.x & 3;           // d-quarter (16 d's)
    const int lz = pos & 3, ly = (pos >> 2) & 3, lx = pos >> 4;
    const int gx = tx + lx, gy = ty + ly, gz = tz + lz;

    const float* qp = q + (size_t)((b * HH + gx) * HH + gy) * HH * DIM
                        + (size_t)gz * DIM + n * HD + qr * 16;
    float4 q0 = reinterpret_cast<const float4*>(qp)[0];
    float4 q1 = reinterpret_cast<const float4*>(qp)[1];
    float4 q2 = reinterpret_cast<const float4*>(qp)[2];
    float4 q3 = reinterpret_cast<const float4*>(qp)[3];
    q0.x *= SCALE; q0.y *= SCALE; q0.z *= SCALE; q0.w *= SCALE;
    q1.x *= SCALE; q1.y *= SCALE; q1.z *= SCALE; q1.w *= SCALE;
    q2.x *= SCALE; q2.y *= SCALE; q2.z *= SCALE; q2.w *= SCALE;
    q3.x *= SCALE; q3.y *= SCALE; q3.z *= SCALE; q3.w *= SCALE;

    float s[K3];
    #pragma unroll
    for (int o = 0; o < K3; ++o) {
        const int di = o / 9, dj = (o / 3) % 3, dl = o % 3;
        const int cidx = ((lx + di) * CY + (ly + dj)) * CZ + (lz + dl);
        const float4* kp = &lk[cidx * CSTRIDE + qr * 4];
        s[o] = dot4(q0, kp[0]) + dot4(q1, kp[1]) + dot4(q2, kp[2]) + dot4(q3, kp[3]);
    }

    // reduce partial dots across the 4 d-split lanes; add rpb
    #pragma unroll
    for (int o = 0; o < K3; ++o) {
        float t = s[o];
        t += __shfl_xor(t, 1);
        t += __shfl_xor(t, 2);
        s[o] = t + rpb[n * K3 + o];
    }

    // softmax over 27 (all 4 lanes redundantly)
    float m = s[0];
    #pragma unroll
    for (int o = 1; o < K3; ++o) m = fmaxf(m, s[o]);
    float psum = 0.f, a0 = 0.f, a1 = 0.f, a2 = 0.f;
    #pragma unroll
    for (int o = 0; o < K3; ++o) {
        const float p = __expf(s[o] - m);
        psum += p;
        a0 = fmaf(p, vv[o * 3 + 0], a0);
        a1 = fmaf(p, vv[o * 3 + 1], a1);
        a2 = fmaf(p, vv[o * 3 + 2], a2);
    }
    const float inv = 1.f / psum;

    if (qr < 3) {
        const float r = (qr == 0 ? a0 : (qr == 1 ? a1 : a2)) * inv;
        out[(((size_t)b * 18 + n * 3 + qr) * HH + gx) * (size_t)(HH * HH)
            + (size_t)gy * HH + gz] = r;
    }
}

} // namespace

extern "C" void kernel_launch(void* const* d_in, const int* in_sizes, int n_in,
                              void* d_out, int out_size, void* d_ws, size_t ws_size,
                              hipStream_t stream)
{
    (void)in_sizes; (void)n_in; (void)d_ws; (void)ws_size; (void)out_size;
    const float* q   = (const float*)d_in[0];
    const float* k   = (const float*)d_in[1];
    const float* rpb = (const float*)d_in[2];
    const float* vv  = (const float*)d_in[3];
    float* out = (float*)d_out;

    const int blocks = 2 * NH * TILES;   // B * NH * tiles = 20736
    natten3d<<<dim3(blocks), dim3(256), 0, stream>>>(q, k, rpb, vv, out);
}

// Round 2
// 374.300 us; speedup vs baseline: 1.2131x; 1.2131x over previous
//
#include <hip/hip_runtime.h>

namespace {

constexpr int HH  = 48;
constexpr int DIM = 384;
constexpr int NH  = 6;
constexpr int K3  = 27;
constexpr float SCALE = 0.125f;   // 64^-0.5

constexpr int TT     = 4;                       // tile edge
constexpr int NCOL   = 216;                     // 6*6*6 halo columns
constexpr int NPAD   = 224;                     // 14 * 16
constexpr int NT     = 14;                      // N-tiles of 16
constexpr int TILES1 = HH / TT;                 // 12
constexpr int TILES  = TILES1 * TILES1 * TILES1;// 1728
constexpr int NBLK   = 2 * NH * TILES;          // 20736 (divisible by 8)

typedef _Float16 half8  __attribute__((ext_vector_type(8)));
typedef float    floatx4 __attribute__((ext_vector_type(4)));

// swizzled byte offset for a [row][64] f16 array (128 B rows):
// XOR row&7 into the 16B-slot bits -> fragment reads are <=2-way banked
__device__ __forceinline__ int swz(int row, int kbyte) {
    return (row * 128 + kbyte) ^ ((row & 7) << 4);
}

__global__ __launch_bounds__(256, 3)
void natten_mfma(const float* __restrict__ q, const float* __restrict__ k,
                 const float* __restrict__ rpb, const float* __restrict__ vv,
                 float* __restrict__ out)
{
    __shared__ _Float16 k_lds[NPAD * 64];   // 28672 B
    __shared__ _Float16 q_lds[64 * 64];     //  8192 B
    __shared__ float    logit_lds[64 * 28]; //  7168 B   total 44032 B

    // bijective XCD swizzle: each XCD gets a contiguous chunk of 2592 blocks
    const int bid0 = blockIdx.x;
    const int bid  = (bid0 & 7) * (NBLK / 8) + (bid0 >> 3);

    // head-fastest: consecutive blocks share the same k/q halo lines
    const int n    = bid % NH;
    const int tile = (bid / NH) % TILES;
    const int b    = bid / (NH * TILES);
    const int tz = (tile % TILES1) * TT;
    const int ty = ((tile / TILES1) % TILES1) * TT;
    const int tx = (tile / (TILES1 * TILES1)) * TT;

    const int tid = threadIdx.x;
    char* kl = (char*)k_lds;
    char* ql = (char*)q_lds;

    // ---------------- stage k halo (f16, swizzled; OOB/pad cols = 0) ----------------
    const float* kb = k + (size_t)b * (HH * HH * HH) * DIM + n * 64;
    #pragma unroll
    for (int it = 0; it < 7; ++it) {                 // 224 cols * 8 chunks / 256
        const int u = it * 256 + tid;
        const int col = u >> 3, ch = u & 7;
        float4 f0 = make_float4(0.f, 0.f, 0.f, 0.f), f1 = f0;
        if (col < NCOL) {
            const int cz = col % 6, cy = (col / 6) % 6, cx = col / 36;
            const int gx = tx + cx - 1, gy = ty + cy - 1, gz = tz + cz - 1;
            if ((unsigned)gx < (unsigned)HH && (unsigned)gy < (unsigned)HH &&
                (unsigned)gz < (unsigned)HH) {
                const float* s = kb + (size_t)((gx * HH + gy) * HH + gz) * DIM + ch * 8;
                f0 = ((const float4*)s)[0];
                f1 = ((const float4*)s)[1];
            }
        }
        half8 h;
        h[0] = (_Float16)f0.x; h[1] = (_Float16)f0.y;
        h[2] = (_Float16)f0.z; h[3] = (_Float16)f0.w;
        h[4] = (_Float16)f1.x; h[5] = (_Float16)f1.y;
        h[6] = (_Float16)f1.z; h[7] = (_Float16)f1.w;
        *(half8*)(kl + swz(col, ch * 16)) = h;
    }

    // ---------------- stage q tile (scaled, f16, swizzled) ----------------
    const float* qb = q + (size_t)b * (HH * HH * HH) * DIM + n * 64;
    #pragma unroll
    for (int it = 0; it < 2; ++it) {                 // 64 rows * 8 chunks / 256
        const int u = it * 256 + tid;
        const int m = u >> 3, ch = u & 7;
        const int lx = m >> 4, ly = (m >> 2) & 3, lz = m & 3;
        const float* s = qb + (size_t)(((tx + lx) * HH + (ty + ly)) * HH + (tz + lz)) * DIM + ch * 8;
        float4 f0 = ((const float4*)s)[0];
        float4 f1 = ((const float4*)s)[1];
        half8 h;
        h[0] = (_Float16)(f0.x * SCALE); h[1] = (_Float16)(f0.y * SCALE);
        h[2] = (_Float16)(f0.z * SCALE); h[3] = (_Float16)(f0.w * SCALE);
        h[4] = (_Float16)(f1.x * SCALE); h[5] = (_Float16)(f1.y * SCALE);
        h[6] = (_Float16)(f1.z * SCALE); h[7] = (_Float16)(f1.w * SCALE);
        *(half8*)(ql + swz(m, ch * 16)) = h;
    }
    __syncthreads();

    // ---------------- dense 16x224 GEMM per wave (M=16 queries, N=224 keys, K=64) ----------------
    const int w = tid >> 6, lane = tid & 63;
    const int lrow = lane & 15, lgrp = lane >> 4;

    const int arow = w * 16 + lrow;
    const half8 a0 = *(const half8*)(ql + swz(arow, 0  + lgrp * 16));
    const half8 a1 = *(const half8*)(ql + swz(arow, 64 + lgrp * 16));

    floatx4 acc[NT];
    #pragma unroll
    for (int nt = 0; nt < NT; ++nt) {
        const int col = nt * 16 + lrow;
        const half8 bf0 = *(const half8*)(kl + swz(col, 0  + lgrp * 16));
        const half8 bf1 = *(const half8*)(kl + swz(col, 64 + lgrp * 16));
        floatx4 c = {0.f, 0.f, 0.f, 0.f};
        c = __builtin_amdgcn_mfma_f32_16x16x32_f16(a0, bf0, c, 0, 0, 0);
        c = __builtin_amdgcn_mfma_f32_16x16x32_f16(a1, bf1, c, 0, 0, 0);
        acc[nt] = c;
    }

    // ---------------- scatter banded entries -> compact [64][28] logits ----------------
    #pragma unroll
    for (int nt = 0; nt < NT; ++nt) {
        const int col = nt * 16 + lrow;
        if (col < NCOL) {
            const int cx = col / 36, cy = (col / 6) % 6, cz = col % 6;
            #pragma unroll
            for (int r = 0; r < 4; ++r) {
                const int m  = w * 16 + lgrp * 4 + r;     // C/D: row=(lane>>4)*4+r, col=lane&15
                const int di = cx - (m >> 4);
                const int dj = cy - ((m >> 2) & 3);
                const int dl = cz - (m & 3);
                if ((unsigned)di <= 2u && (unsigned)dj <= 2u && (unsigned)dl <= 2u) {
                    logit_lds[m * 28 + (di * 3 + dj) * 3 + dl] = acc[nt][r];
                }
            }
        }
    }
    __syncthreads();

    // ---------------- softmax over 27 + attn*v ----------------
    {
        const int qi = tid >> 2, p = tid & 3;     // 4 threads/query, p=0..2 write outputs
        float s[28];
        const float4* row4 = (const float4*)(logit_lds + qi * 28);
        #pragma unroll
        for (int j = 0; j < 7; ++j) ((float4*)s)[j] = row4[j];

        const float* rp = rpb + n * K3;
        float mx = -1e30f;
        #pragma unroll
        for (int o = 0; o < K3; ++o) { s[o] += rp[o]; mx = fmaxf(mx, s[o]); }

        float den = 0.f, num = 0.f;
        #pragma unroll
        for (int o = 0; o < K3; ++o) {
            const float e = __expf(s[o] - mx);
            den += e;
            if (p < 3) num = fmaf(e, vv[o * 3 + p], num);
        }
        if (p < 3) {
            const int lx = qi >> 4, ly = (qi >> 2) & 3, lz = qi & 3;
            out[((size_t)(b * 18 + n * 3 + p) * HH + (tx + lx)) * (size_t)(HH * HH)
                + (size_t)(ty + ly) * HH + (tz + lz)] = num / den;
        }
    }
}

} // namespace

extern "C" void kernel_launch(void* const* d_in, const int* in_sizes, int n_in,
                              void* d_out, int out_size, void* d_ws, size_t ws_size,
                              hipStream_t stream)
{
    (void)in_sizes; (void)n_in; (void)d_ws; (void)ws_size; (void)out_size;
    const float* q   = (const float*)d_in[0];
    const float* k   = (const float*)d_in[1];
    const float* rpb = (const float*)d_in[2];
    const float* vv  = (const float*)d_in[3];
    float* out = (float*)d_out;

    natten_mfma<<<dim3(NBLK), dim3(256), 0, stream>>>(q, k, rpb, vv, out);
}

// Round 4
// 199.495 us; speedup vs baseline: 2.2761x; 1.8762x over previous
//
#include <hip/hip_runtime.h>

namespace {

constexpr int HH  = 48;
constexpr int DIM = 384;
constexpr int NH  = 6;
constexpr int K3  = 27;
constexpr float SCALE = 0.125f;   // 64^-0.5

constexpr int TT     = 4;
constexpr int NPAD   = 224;                     // staged halo cols (216 + 8 pad)
constexpr int NT     = 7;                       // per-wave 16-col slabs (112 cols @ w*36)
constexpr int TILES1 = HH / TT;                 // 12
constexpr int TILES  = TILES1 * TILES1 * TILES1;// 1728
constexpr int NBLK   = 2 * NH * TILES;          // 20736 (div by 8)

typedef _Float16 half8  __attribute__((ext_vector_type(8)));
typedef _Float16 half2v __attribute__((ext_vector_type(2)));
typedef __fp16   fp16x2 __attribute__((ext_vector_type(2)));
typedef float    floatx4 __attribute__((ext_vector_type(4)));

__device__ __forceinline__ half2v pk(float a, float b) {
    fp16x2 t = __builtin_amdgcn_cvt_pkrtz(a, b);
    return __builtin_bit_cast(half2v, t);
}

__global__ __launch_bounds__(256, 4)
void natten_mfma2(const float* __restrict__ q, const float* __restrict__ k,
                  const float* __restrict__ rpb, const float* __restrict__ vv,
                  float* __restrict__ out)
{
    __shared__ _Float16 k_lds[NPAD * 64];    // 28672 B, swizzled
    __shared__ float    logit_lds[64 * 28];  //  7168 B
    __shared__ float4   rv_lds[K3];          //   432 B  {v0,v1,v2,rpb}

    const int bid0 = blockIdx.x;
    const int bid  = (bid0 & 7) * (NBLK / 8) + (bid0 >> 3);   // bijective XCD swizzle

    const int n    = bid % NH;                 // head-fastest for L2 sharing
    const int tile = (bid / NH) % TILES;
    const int b    = bid / (NH * TILES);
    const int tz = (tile % TILES1) * TT;
    const int ty = ((tile / TILES1) % TILES1) * TT;
    const int tx = (tile / (TILES1 * TILES1)) * TT;

    const int tid = threadIdx.x;
    char* kl = (char*)k_lds;

    if (tid < K3) {
        rv_lds[tid] = make_float4(vv[tid * 3], vv[tid * 3 + 1], vv[tid * 3 + 2],
                                  rpb[n * K3 + tid]);
    }

    // ---------------- stage k halo (f16, swizzled; OOB = 0) ----------------
    // thread: col0 = tid>>3 in [0,32), chunk ch = tid&7 (16B f16 = 32B f32 src)
    // iterates col = col0 + it*32; base-6 decomposition via carry updates.
    const float* kb = k + (size_t)b * (HH * HH * HH) * DIM + n * 64;
    {
        const int col0 = tid >> 3;
        const int ch   = tid & 7;
        int cx = 0, cy = col0 / 6, cz = col0 - (col0 / 6) * 6;
        const int xm = (col0 & 7) << 4;                 // col&7 invariant under +32
        char* dst = kl + col0 * 128 + ((ch * 16) ^ xm);
        #pragma unroll
        for (int it = 0; it < 7; ++it) {
            const int gx = tx + cx - 1, gy = ty + cy - 1, gz = tz + cz - 1;
            float4 f0 = make_float4(0.f, 0.f, 0.f, 0.f), f1 = f0;
            if ((unsigned)gx < 48u && (unsigned)gy < 48u && (unsigned)gz < 48u) {
                const float* s = kb + (size_t)((gx * 48 + gy) * 48 + gz) * DIM + ch * 8;
                f0 = ((const float4*)s)[0];
                f1 = ((const float4*)s)[1];
            }
            half8 h;
            ((half2v*)&h)[0] = pk(f0.x, f0.y);
            ((half2v*)&h)[1] = pk(f0.z, f0.w);
            ((half2v*)&h)[2] = pk(f1.x, f1.y);
            ((half2v*)&h)[3] = pk(f1.z, f1.w);
            *(half8*)(dst + it * 4096) = h;
            cz += 2; if (cz >= 6) { cz -= 6; cy += 1; }     // += 32 = (0,5,2) base-6
            cy += 5; if (cy >= 6) { cy -= 6; cx += 1; }
        }
    }

    // ---------------- A fragments: q direct to registers (unscaled) ----------------
    const int w = tid >> 6, lane = tid & 63;
    const int lrow = lane & 15, lgrp = lane >> 4;
    half8 a0, a1;
    {
        const float* qp = q + (size_t)b * (HH * HH * HH) * DIM
            + (size_t)(((tx + w) * 48 + (ty + (lrow >> 2))) * 48 + (tz + (lrow & 3))) * DIM
            + n * 64 + lgrp * 8;
        float4 f0 = ((const float4*)qp)[0];
        float4 f1 = ((const float4*)qp)[1];
        float4 g0 = ((const float4*)(qp + 32))[0];
        float4 g1 = ((const float4*)(qp + 32))[1];
        ((half2v*)&a0)[0] = pk(f0.x, f0.y);
        ((half2v*)&a0)[1] = pk(f0.z, f0.w);
        ((half2v*)&a0)[2] = pk(f1.x, f1.y);
        ((half2v*)&a0)[3] = pk(f1.z, f1.w);
        ((half2v*)&a1)[0] = pk(g0.x, g0.y);
        ((half2v*)&a1)[1] = pk(g0.z, g0.w);
        ((half2v*)&a1)[2] = pk(g1.x, g1.y);
        ((half2v*)&a1)[3] = pk(g1.z, g1.w);
    }
    __syncthreads();

    // ---------------- GEMM: wave w covers cols [w*36, w*36+112) ----------------
    const int cbase = w * 36 + lrow;
    const int xm2 = (cbase & 7) << 4;                     // invariant under +16
    const char* bpA = kl + cbase * 128 + ((lgrp * 16) ^ xm2);
    const char* bpB = kl + cbase * 128 + ((lgrp * 16 + 64) ^ xm2);
    floatx4 acc[NT];
    #pragma unroll
    for (int nt = 0; nt < NT; ++nt) {
        const half8 b0 = *(const half8*)(bpA + nt * 2048);
        const half8 b1 = *(const half8*)(bpB + nt * 2048);
        floatx4 c = {0.f, 0.f, 0.f, 0.f};
        c = __builtin_amdgcn_mfma_f32_16x16x32_f16(a0, b0, c, 0, 0, 0);
        c = __builtin_amdgcn_mfma_f32_16x16x32_f16(a1, b1, c, 0, 0, 0);
        acc[nt] = c;
    }

    // ---------------- scatter banded entries -> [64][28] ----------------
    // rel = nt*16 + lrow = rx*36 + ry*6 + rz; query m=(w,lgrp,r) => di=rx, dj=ry-lgrp, dl=rz-r
    {
        const int ly6 = lrow >= 12 ? 2 : (lrow >= 6 ? 1 : 0);
        const int lz6 = lrow - ly6 * 6;
        const int base0 = (w * 16 + lgrp * 4) * 112;      // byte offset of row m(r=0)
        constexpr int Nx[NT] = {0, 0, 0, 1, 1, 2, 2};
        constexpr int Ny[NT] = {0, 2, 5, 2, 4, 1, 4};
        constexpr int Nz[NT] = {0, 4, 2, 0, 4, 2, 0};
        #pragma unroll
        for (int nt = 0; nt < NT; ++nt) {
            int rz = lz6 + Nz[nt];
            int ry = ly6 + Ny[nt];
            if (rz >= 6) { rz -= 6; ry += 1; }
            int rx = Nx[nt];
            if (ry >= 6) { ry -= 6; rx += 1; }
            const int dj = ry - lgrp;
            if (rx <= 2 && (unsigned)dj <= 2u) {
                const int sl0 = (rx * 3 + dj) * 3 + rz;   // slot(r) = sl0 - r
                #pragma unroll
                for (int r = 0; r < 4; ++r) {
                    if ((unsigned)(rz - r) <= 2u) {
                        *(float*)((char*)logit_lds + base0 + r * 112 + (sl0 - r) * 4)
                            = acc[nt][r];
                    }
                }
            }
        }
    }
    __syncthreads();

    // ---------------- softmax: 4 threads/query, o = p mod 4 ----------------
    {
        const int qi = tid >> 2, p = tid & 3;
        const float* lp = logit_lds + qi * 28;
        float t[7];
        float mx = -1e30f;
        #pragma unroll
        for (int j = 0; j < 7; ++j) {
            const int o = p + 4 * j;
            if (o < K3) {
                t[j] = fmaf(lp[o], SCALE, rv_lds[o].w);
                mx = fmaxf(mx, t[j]);
            }
        }
        mx = fmaxf(mx, __shfl_xor(mx, 1));
        mx = fmaxf(mx, __shfl_xor(mx, 2));
        float den = 0.f, n0 = 0.f, n1 = 0.f, n2 = 0.f;
        #pragma unroll
        for (int j = 0; j < 7; ++j) {
            const int o = p + 4 * j;
            if (o < K3) {
                const float e = __expf(t[j] - mx);
                const float4 rv = rv_lds[o];
                den += e;
                n0 = fmaf(e, rv.x, n0);
                n1 = fmaf(e, rv.y, n1);
                n2 = fmaf(e, rv.z, n2);
            }
        }
        den += __shfl_xor(den, 1); den += __shfl_xor(den, 2);
        n0  += __shfl_xor(n0, 1);  n0  += __shfl_xor(n0, 2);
        n1  += __shfl_xor(n1, 1);  n1  += __shfl_xor(n1, 2);
        n2  += __shfl_xor(n2, 1);  n2  += __shfl_xor(n2, 2);
        if (p < 3) {
            const float res = (p == 0 ? n0 : (p == 1 ? n1 : n2)) / den;
            out[((size_t)(b * 18 + n * 3 + p) * HH + (tx + (qi >> 4))) * (size_t)(HH * HH)
                + (size_t)(ty + ((qi >> 2) & 3)) * HH + (tz + (qi & 3))] = res;
        }
    }
}

} // namespace

extern "C" void kernel_launch(void* const* d_in, const int* in_sizes, int n_in,
                              void* d_out, int out_size, void* d_ws, size_t ws_size,
                              hipStream_t stream)
{
    (void)in_sizes; (void)n_in; (void)d_ws; (void)ws_size; (void)out_size;
    const float* q   = (const float*)d_in[0];
    const float* k   = (const float*)d_in[1];
    const float* rpb = (const float*)d_in[2];
    const float* vv  = (const float*)d_in[3];
    float* out = (float*)d_out;

    natten_mfma2<<<dim3(NBLK), dim3(256), 0, stream>>>(q, k, rpb, vv, out);
}

// Round 5
// 198.032 us; speedup vs baseline: 2.2929x; 1.0074x over previous
//
#include <hip/hip_runtime.h>

namespace {

constexpr int HH  = 48;
constexpr int DIM = 384;
constexpr int NH  = 6;
constexpr int K3  = 27;
constexpr float L2E    = 1.44269504088896f;
constexpr float SCALE2 = 0.125f * L2E;          // 64^-0.5 * log2(e)

constexpr int TT     = 4;
constexpr int NPAD   = 224;
constexpr int NT     = 7;                       // per-wave 16-col slabs (112 cols @ w*36)
constexpr int TILES1 = HH / TT;                 // 12
constexpr int TILES  = TILES1 * TILES1 * TILES1;// 1728
constexpr int NBLK   = 2 * NH * TILES;          // 20736 (div by 8)

typedef _Float16 half8  __attribute__((ext_vector_type(8)));
typedef _Float16 half2v __attribute__((ext_vector_type(2)));
typedef __fp16   fp16x2 __attribute__((ext_vector_type(2)));
typedef float    floatx4 __attribute__((ext_vector_type(4)));

__device__ __forceinline__ half2v pk(float a, float b) {
    fp16x2 t = __builtin_amdgcn_cvt_pkrtz(a, b);
    return __builtin_bit_cast(half2v, t);
}

__global__ __launch_bounds__(256, 5)
void natten_mfma3(const float* __restrict__ q, const float* __restrict__ k,
                  const float* __restrict__ rpb, const float* __restrict__ vv,
                  float* __restrict__ out)
{
    // logits alias the first 7168 B of k_lds (k dead after GEMM; barrier separates)
    __shared__ _Float16 k_lds[NPAD * 64];    // 28672 B, swizzled
    __shared__ float4   rv_lds[K3];          //   432 B  {v0,v1,v2,rpb*log2e}
    float* logit_lds = (float*)k_lds;

    const int bid0 = blockIdx.x;
    const int bid  = (bid0 & 7) * (NBLK / 8) + (bid0 >> 3);   // bijective XCD swizzle

    const int n    = bid % NH;                 // head-fastest for L2 sharing
    const int tile = (bid / NH) % TILES;
    const int b    = bid / (NH * TILES);
    const int tz = (tile % TILES1) * TT;
    const int ty = ((tile / TILES1) % TILES1) * TT;
    const int tx = (tile / (TILES1 * TILES1)) * TT;

    const int tid = threadIdx.x;
    char* kl = (char*)k_lds;

    if (tid < K3) {
        rv_lds[tid] = make_float4(vv[tid * 3], vv[tid * 3 + 1], vv[tid * 3 + 2],
                                  rpb[n * K3 + tid] * L2E);
    }

    // ---------------- stage k halo: phase A = issue ALL loads (clamped, unconditional)
    const float* kb = k + (size_t)b * (HH * HH * HH) * DIM + n * 64;
    const int col0 = tid >> 3;
    const int ch   = tid & 7;
    char* dst = kl + col0 * 128 + ((ch * 16) ^ ((col0 & 7) << 4));

    float4 F0[7], F1[7];
    float  MS[7];
    {
        int cx = 0, cy = col0 / 6, cz = col0 - (col0 / 6) * 6;
        #pragma unroll
        for (int it = 0; it < 7; ++it) {
            const int gx = tx + cx - 1, gy = ty + cy - 1, gz = tz + cz - 1;
            const bool valid = ((unsigned)gx < 48u) && ((unsigned)gy < 48u) &&
                               ((unsigned)gz < 48u);
            const int cgx = min(max(gx, 0), 47);
            const int cgy = min(max(gy, 0), 47);
            const int cgz = min(max(gz, 0), 47);
            const float* s = kb + (size_t)((cgx * 48 + cgy) * 48 + cgz) * DIM + ch * 8;
            F0[it] = ((const float4*)s)[0];
            F1[it] = ((const float4*)s)[1];
            MS[it] = valid ? 1.f : 0.f;
            cz += 2; if (cz >= 6) { cz -= 6; cy += 1; }     // +32 = (0,5,2) base-6
            cy += 5; if (cy >= 6) { cy -= 6; cx += 1; }
        }
    }

    // q loads issued while k loads are in flight
    const int w = tid >> 6, lane = tid & 63;
    const int lrow = lane & 15, lgrp = lane >> 4;
    const float* qp = q + (size_t)b * (HH * HH * HH) * DIM
        + (size_t)(((tx + w) * 48 + (ty + (lrow >> 2))) * 48 + (tz + (lrow & 3))) * DIM
        + n * 64 + lgrp * 8;
    const float4 qf0 = ((const float4*)qp)[0];
    const float4 qf1 = ((const float4*)qp)[1];
    const float4 qg0 = ((const float4*)(qp + 32))[0];
    const float4 qg1 = ((const float4*)(qp + 32))[1];

    // ---------------- phase B: convert + LDS write as loads drain
    #pragma unroll
    for (int it = 0; it < 7; ++it) {
        const float m = MS[it];
        half8 h;
        ((half2v*)&h)[0] = pk(F0[it].x * m, F0[it].y * m);
        ((half2v*)&h)[1] = pk(F0[it].z * m, F0[it].w * m);
        ((half2v*)&h)[2] = pk(F1[it].x * m, F1[it].y * m);
        ((half2v*)&h)[3] = pk(F1[it].z * m, F1[it].w * m);
        *(half8*)(dst + it * 4096) = h;
    }

    half8 a0, a1;
    ((half2v*)&a0)[0] = pk(qf0.x, qf0.y);
    ((half2v*)&a0)[1] = pk(qf0.z, qf0.w);
    ((half2v*)&a0)[2] = pk(qf1.x, qf1.y);
    ((half2v*)&a0)[3] = pk(qf1.z, qf1.w);
    ((half2v*)&a1)[0] = pk(qg0.x, qg0.y);
    ((half2v*)&a1)[1] = pk(qg0.z, qg0.w);
    ((half2v*)&a1)[2] = pk(qg1.x, qg1.y);
    ((half2v*)&a1)[3] = pk(qg1.z, qg1.w);
    __syncthreads();

    // ---------------- GEMM: wave w covers cols [w*36, w*36+112) ----------------
    const int cbase = w * 36 + lrow;
    const int xm2 = (cbase & 7) << 4;                     // invariant under +16
    const char* bpA = kl + cbase * 128 + ((lgrp * 16) ^ xm2);
    const char* bpB = kl + cbase * 128 + ((lgrp * 16 + 64) ^ xm2);
    floatx4 acc[NT];
    #pragma unroll
    for (int nt = 0; nt < NT; ++nt) {
        const half8 b0 = *(const half8*)(bpA + nt * 2048);
        const half8 b1 = *(const half8*)(bpB + nt * 2048);
        floatx4 c = {0.f, 0.f, 0.f, 0.f};
        c = __builtin_amdgcn_mfma_f32_16x16x32_f16(a0, b0, c, 0, 0, 0);
        c = __builtin_amdgcn_mfma_f32_16x16x32_f16(a1, b1, c, 0, 0, 0);
        acc[nt] = c;
    }
    __syncthreads();   // all k reads done before logits overwrite k_lds

    // ---------------- scatter banded entries -> [64][28] (aliased region) ----------
    {
        const int ly6 = lrow >= 12 ? 2 : (lrow >= 6 ? 1 : 0);
        const int lz6 = lrow - ly6 * 6;
        const int base0 = (w * 16 + lgrp * 4) * 112;      // byte offset of row m(r=0)
        constexpr int Nx[NT] = {0, 0, 0, 1, 1, 2, 2};
        constexpr int Ny[NT] = {0, 2, 5, 2, 4, 1, 4};
        constexpr int Nz[NT] = {0, 4, 2, 0, 4, 2, 0};
        #pragma unroll
        for (int nt = 0; nt < NT; ++nt) {
            int rz = lz6 + Nz[nt];
            int ry = ly6 + Ny[nt];
            if (rz >= 6) { rz -= 6; ry += 1; }
            int rx = Nx[nt];
            if (ry >= 6) { ry -= 6; rx += 1; }
            const int dj = ry - lgrp;
            if (rx <= 2 && (unsigned)dj <= 2u) {
                const int sl0 = (rx * 3 + dj) * 3 + rz;   // slot(r) = sl0 - r
                #pragma unroll
                for (int r = 0; r < 4; ++r) {
                    if ((unsigned)(rz - r) <= 2u) {
                        *(float*)((char*)logit_lds + base0 + r * 112 + (sl0 - r) * 4)
                            = acc[nt][r];
                    }
                }
            }
        }
    }
    __syncthreads();

    // ---------------- softmax (exp2 domain): 4 threads/query, o = p mod 4 --------
    {
        const int qi = tid >> 2, p = tid & 3;
        const float* lp = logit_lds + qi * 28;
        float t[7];
        float mx = -1e30f;
        #pragma unroll
        for (int j = 0; j < 7; ++j) {
            const int o = p + 4 * j;
            if (o < K3) {
                t[j] = fmaf(lp[o], SCALE2, rv_lds[o].w);
                mx = fmaxf(mx, t[j]);
            }
        }
        mx = fmaxf(mx, __shfl_xor(mx, 1));
        mx = fmaxf(mx, __shfl_xor(mx, 2));
        float den = 0.f, n0 = 0.f, n1 = 0.f, n2 = 0.f;
        #pragma unroll
        for (int j = 0; j < 7; ++j) {
            const int o = p + 4 * j;
            if (o < K3) {
                const float e = __builtin_amdgcn_exp2f(t[j] - mx);
                const float4 rv = rv_lds[o];
                den += e;
                n0 = fmaf(e, rv.x, n0);
                n1 = fmaf(e, rv.y, n1);
                n2 = fmaf(e, rv.z, n2);
            }
        }
        den += __shfl_xor(den, 1); den += __shfl_xor(den, 2);
        n0  += __shfl_xor(n0, 1);  n0  += __shfl_xor(n0, 2);
        n1  += __shfl_xor(n1, 1);  n1  += __shfl_xor(n1, 2);
        n2  += __shfl_xor(n2, 1);  n2  += __shfl_xor(n2, 2);
        if (p < 3) {
            const float res = (p == 0 ? n0 : (p == 1 ? n1 : n2)) / den;
            out[((size_t)(b * 18 + n * 3 + p) * HH + (tx + (qi >> 4))) * (size_t)(HH * HH)
                + (size_t)(ty + ((qi >> 2) & 3)) * HH + (tz + (qi & 3))] = res;
        }
    }
}

} // namespace

extern "C" void kernel_launch(void* const* d_in, const int* in_sizes, int n_in,
                              void* d_out, int out_size, void* d_ws, size_t ws_size,
                              hipStream_t stream)
{
    (void)in_sizes; (void)n_in; (void)d_ws; (void)ws_size; (void)out_size;
    const float* q   = (const float*)d_in[0];
    const float* k   = (const float*)d_in[1];
    const float* rpb = (const float*)d_in[2];
    const float* vv  = (const float*)d_in[3];
    float* out = (float*)d_out;

    natten_mfma3<<<dim3(NBLK), dim3(256), 0, stream>>>(q, k, rpb, vv, out);
}

// Round 6
// 193.376 us; speedup vs baseline: 2.3481x; 1.0241x over previous
//
#include <hip/hip_runtime.h>

namespace {

constexpr int HH  = 48;
constexpr int DIM = 384;
constexpr int NH  = 6;
constexpr int K3  = 27;
constexpr float L2E    = 1.44269504088896f;
constexpr float SCALE2 = 0.125f * L2E;          // 64^-0.5 * log2(e)

constexpr int TT     = 4;
constexpr int NPAD   = 224;
constexpr int NT     = 7;                       // per-wave 16-col slabs (112 cols @ w*36)
constexpr int TILES1 = HH / TT;                 // 12
constexpr int TILES  = TILES1 * TILES1 * TILES1;// 1728
constexpr int NBLK   = 2 * NH * TILES;          // 20736 (div by 8)

typedef _Float16 half8  __attribute__((ext_vector_type(8)));
typedef _Float16 half2v __attribute__((ext_vector_type(2)));
typedef __fp16   fp16x2 __attribute__((ext_vector_type(2)));
typedef float    floatx4 __attribute__((ext_vector_type(4)));

__device__ __forceinline__ half2v pk(float a, float b) {
    fp16x2 t = __builtin_amdgcn_cvt_pkrtz(a, b);
    return __builtin_bit_cast(half2v, t);
}

__global__ __launch_bounds__(256, 4)
void natten_mfma4(const float* __restrict__ q, const float* __restrict__ k,
                  const float* __restrict__ rpb, const float* __restrict__ vv,
                  float* __restrict__ out)
{
    __shared__ _Float16 k_lds[NPAD * 64];    // 28672 B, swizzled
    __shared__ float    logit_lds[64 * 28];  //  7168 B
    __shared__ float4   rv_lds[K3];          //   432 B   total 36272 B -> 4 blocks/CU

    const int bid0 = blockIdx.x;
    const int bid  = (bid0 & 7) * (NBLK / 8) + (bid0 >> 3);   // bijective XCD swizzle

    const int n    = bid % NH;                 // head-fastest for L2 sharing
    const int tile = (bid / NH) % TILES;
    const int b    = bid / (NH * TILES);
    const int tz = (tile % TILES1) * TT;
    const int ty = ((tile / TILES1) % TILES1) * TT;
    const int tx = (tile / (TILES1 * TILES1)) * TT;

    const int tid = threadIdx.x;
    char* kl = (char*)k_lds;

    if (tid < K3) {
        rv_lds[tid] = make_float4(vv[tid * 3], vv[tid * 3 + 1], vv[tid * 3 + 2],
                                  rpb[n * K3 + tid] * L2E);
    }

    // ================= phase A: ISSUE all global loads (no uses) =================
    const float* kb = k + (size_t)b * (HH * HH * HH) * DIM + n * 64;
    const int col0 = tid >> 3;
    const int ch   = tid & 7;
    char* dst = kl + col0 * 128 + ((ch * 16) ^ ((col0 & 7) << 4));

    float4 F0[7], F1[7];
    float  MS[7];
    {
        int cx = 0, cy = col0 / 6, cz = col0 - (col0 / 6) * 6;
        #pragma unroll
        for (int it = 0; it < 7; ++it) {
            const int gx = tx + cx - 1, gy = ty + cy - 1, gz = tz + cz - 1;
            const bool valid = ((unsigned)gx < 48u) && ((unsigned)gy < 48u) &&
                               ((unsigned)gz < 48u);
            const int cgx = min(max(gx, 0), 47);
            const int cgy = min(max(gy, 0), 47);
            const int cgz = min(max(gz, 0), 47);
            const float* s = kb + (size_t)((cgx * 48 + cgy) * 48 + cgz) * DIM + ch * 8;
            F0[it] = ((const float4*)s)[0];
            F1[it] = ((const float4*)s)[1];
            MS[it] = valid ? 1.f : 0.f;
            cz += 2; if (cz >= 6) { cz -= 6; cy += 1; }     // +32 = (0,5,2) base-6
            cy += 5; if (cy >= 6) { cy -= 6; cx += 1; }
        }
    }

    const int w = tid >> 6, lane = tid & 63;
    const int lrow = lane & 15, lgrp = lane >> 4;
    const float* qp = q + (size_t)b * (HH * HH * HH) * DIM
        + (size_t)(((tx + w) * 48 + (ty + (lrow >> 2))) * 48 + (tz + (lrow & 3))) * DIM
        + n * 64 + lgrp * 8;
    const float4 qf0 = ((const float4*)qp)[0];
    const float4 qf1 = ((const float4*)qp)[1];
    const float4 qg0 = ((const float4*)(qp + 32))[0];
    const float4 qg1 = ((const float4*)(qp + 32))[1];

    // keep ALL 18 loads in flight: nothing may be scheduled across this point
    __builtin_amdgcn_sched_barrier(0);

    // ================= phase B: convert + LDS write as loads drain ===============
    #pragma unroll
    for (int it = 0; it < 7; ++it) {
        const float m = MS[it];
        half8 h;
        ((half2v*)&h)[0] = pk(F0[it].x * m, F0[it].y * m);
        ((half2v*)&h)[1] = pk(F0[it].z * m, F0[it].w * m);
        ((half2v*)&h)[2] = pk(F1[it].x * m, F1[it].y * m);
        ((half2v*)&h)[3] = pk(F1[it].z * m, F1[it].w * m);
        *(half8*)(dst + it * 4096) = h;
    }

    half8 a0, a1;
    ((half2v*)&a0)[0] = pk(qf0.x, qf0.y);
    ((half2v*)&a0)[1] = pk(qf0.z, qf0.w);
    ((half2v*)&a0)[2] = pk(qf1.x, qf1.y);
    ((half2v*)&a0)[3] = pk(qf1.z, qf1.w);
    ((half2v*)&a1)[0] = pk(qg0.x, qg0.y);
    ((half2v*)&a1)[1] = pk(qg0.z, qg0.w);
    ((half2v*)&a1)[2] = pk(qg1.x, qg1.y);
    ((half2v*)&a1)[3] = pk(qg1.z, qg1.w);
    __syncthreads();                     // the only block-wide barrier

    // ================= GEMM: wave w covers cols [w*36, w*36+112) =================
    const int cbase = w * 36 + lrow;
    const int xm2 = (cbase & 7) << 4;                     // invariant under +16
    const char* bpA = kl + cbase * 128 + ((lgrp * 16) ^ xm2);
    const char* bpB = kl + cbase * 128 + ((lgrp * 16 + 64) ^ xm2);
    floatx4 acc[NT];
    #pragma unroll
    for (int nt = 0; nt < NT; ++nt) {
        const half8 b0 = *(const half8*)(bpA + nt * 2048);
        const half8 b1 = *(const half8*)(bpB + nt * 2048);
        floatx4 c = {0.f, 0.f, 0.f, 0.f};
        c = __builtin_amdgcn_mfma_f32_16x16x32_f16(a0, b0, c, 0, 0, 0);
        c = __builtin_amdgcn_mfma_f32_16x16x32_f16(a1, b1, c, 0, 0, 0);
        acc[nt] = c;
    }

    // ===== scatter banded entries -> [64][28]; intra-wave consumer, no barrier ====
    {
        const int ly6 = lrow >= 12 ? 2 : (lrow >= 6 ? 1 : 0);
        const int lz6 = lrow - ly6 * 6;
        const int base0 = (w * 16 + lgrp * 4) * 112;      // byte offset of row m(r=0)
        constexpr int Nx[NT] = {0, 0, 0, 1, 1, 2, 2};
        constexpr int Ny[NT] = {0, 2, 5, 2, 4, 1, 4};
        constexpr int Nz[NT] = {0, 4, 2, 0, 4, 2, 0};
        #pragma unroll
        for (int nt = 0; nt < NT; ++nt) {
            int rz = lz6 + Nz[nt];
            int ry = ly6 + Ny[nt];
            if (rz >= 6) { rz -= 6; ry += 1; }
            int rx = Nx[nt];
            if (ry >= 6) { ry -= 6; rx += 1; }
            const int dj = ry - lgrp;
            if (rx <= 2 && (unsigned)dj <= 2u) {
                const int sl0 = (rx * 3 + dj) * 3 + rz;   // slot(r) = sl0 - r
                #pragma unroll
                for (int r = 0; r < 4; ++r) {
                    if ((unsigned)(rz - r) <= 2u) {
                        *(float*)((char*)logit_lds + base0 + r * 112 + (sl0 - r) * 4)
                            = acc[nt][r];
                    }
                }
            }
        }
    }
    // wave w wrote exactly rows [16w,16w+16); the same wave reads them below.
    // compiler orders the dependent ds ops with lgkmcnt — no s_barrier needed.

    // ============ softmax (exp2 domain): 4 threads/query, o = p mod 4 ============
    {
        const int qi = tid >> 2, p = tid & 3;
        const float* lp = logit_lds + qi * 28;
        float t[7];
        float mx = -1e30f;
        #pragma unroll
        for (int j = 0; j < 7; ++j) {
            const int o = p + 4 * j;
            if (o < K3) {
                t[j] = fmaf(lp[o], SCALE2, rv_lds[o].w);
                mx = fmaxf(mx, t[j]);
            }
        }
        mx = fmaxf(mx, __shfl_xor(mx, 1));
        mx = fmaxf(mx, __shfl_xor(mx, 2));
        float den = 0.f, n0 = 0.f, n1 = 0.f, n2 = 0.f;
        #pragma unroll
        for (int j = 0; j < 7; ++j) {
            const int o = p + 4 * j;
            if (o < K3) {
                const float e = __builtin_amdgcn_exp2f(t[j] - mx);
                const float4 rv = rv_lds[o];
                den += e;
                n0 = fmaf(e, rv.x, n0);
                n1 = fmaf(e, rv.y, n1);
                n2 = fmaf(e, rv.z, n2);
            }
        }
        den += __shfl_xor(den, 1); den += __shfl_xor(den, 2);
        n0  += __shfl_xor(n0, 1);  n0  += __shfl_xor(n0, 2);
        n1  += __shfl_xor(n1, 1);  n1  += __shfl_xor(n1, 2);
        n2  += __shfl_xor(n2, 1);  n2  += __shfl_xor(n2, 2);
        if (p < 3) {
            const float res = (p == 0 ? n0 : (p == 1 ? n1 : n2)) / den;
            out[((size_t)(b * 18 + n * 3 + p) * HH + (tx + (qi >> 4))) * (size_t)(HH * HH)
                + (size_t)(ty + ((qi >> 2) & 3)) * HH + (tz + (qi & 3))] = res;
        }
    }
}

} // namespace

extern "C" void kernel_launch(void* const* d_in, const int* in_sizes, int n_in,
                              void* d_out, int out_size, void* d_ws, size_t ws_size,
                              hipStream_t stream)
{
    (void)in_sizes; (void)n_in; (void)d_ws; (void)ws_size; (void)out_size;
    const float* q   = (const float*)d_in[0];
    const float* k   = (const float*)d_in[1];
    const float* rpb = (const float*)d_in[2];
    const float* vv  = (const float*)d_in[3];
    float* out = (float*)d_out;

    natten_mfma4<<<dim3(NBLK), dim3(256), 0, stream>>>(q, k, rpb, vv, out);
}